// Round 2
// baseline (476.269 us; speedup 1.0000x reference)
//
#include <hip/hip_runtime.h>

typedef unsigned short u16;
typedef unsigned int u32;
typedef __bf16 bf16x8 __attribute__((ext_vector_type(8)));
typedef float f32x4 __attribute__((ext_vector_type(4)));

#define DEV static __device__ __forceinline__

DEV u16 f2bf(float x) {
    union { float f; u32 u; } v; v.f = x;
    u32 r = (v.u + 0x7FFFu + ((v.u >> 16) & 1u)) >> 16;
    return (u16)r;
}

DEV void store_c(float* p, float v) { *p = v; }
DEV void store_c(u16* p, float v) { *p = f2bf(v); }

// swizzled LDS byte offset: row stride 128B, XOR bits 4-6 with (row&7)
DEV int swz(int row, int bytecol) { return row * 128 + (bytecol ^ ((row & 7) << 4)); }

// ---------------------------------------------------------------------------
// pack zc = concat(z, connection) as bf16  [8192 x 2048]
// ---------------------------------------------------------------------------
__global__ void pack_zc(const float* __restrict__ z, const float* __restrict__ cn,
                        u16* __restrict__ zc) {
    size_t i = ((size_t)blockIdx.x * blockDim.x + threadIdx.x) * 4;
    size_t t = i >> 11;            // token
    int c = (int)(i & 2047);
    const float* src = (c < 1024) ? (z + t * 1024 + c) : (cn + t * 1024 + (c - 1024));
    float4 v = *reinterpret_cast<const float4*>(src);
    u32 lo = (u32)f2bf(v.x) | ((u32)f2bf(v.y) << 16);
    u32 hi = (u32)f2bf(v.z) | ((u32)f2bf(v.w) << 16);
    *reinterpret_cast<uint2*>(zc + i) = make_uint2(lo, hi);
}

// ---------------------------------------------------------------------------
// W [K x N] fp32  ->  WT [N x K] bf16
// ---------------------------------------------------------------------------
__global__ void transpose_conv_w(const float* __restrict__ W, u16* __restrict__ WT,
                                 int K, int N) {
    __shared__ float tile[32][33];
    int n0 = blockIdx.x * 32, k0 = blockIdx.y * 32;
    int tx = threadIdx.x, ty = threadIdx.y;
    #pragma unroll
    for (int i = ty; i < 32; i += 8)
        tile[i][tx] = W[(size_t)(k0 + i) * N + n0 + tx];
    __syncthreads();
    #pragma unroll
    for (int i = ty; i < 32; i += 8)
        WT[(size_t)(n0 + i) * K + k0 + tx] = f2bf(tile[tx][i]);
}

// ---------------------------------------------------------------------------
// Vflat [8192 x 1024] bf16 -> Vt [64(bh)][64(hd)][2048(L)] bf16
// ---------------------------------------------------------------------------
__global__ void transpose_v(const u16* __restrict__ Vf, u16* __restrict__ Vt) {
    __shared__ u16 tile[32][33];
    int bh = blockIdx.z; int b = bh >> 4, h = bh & 15;
    int l0 = blockIdx.x * 32, d0 = blockIdx.y * 32;
    int tx = threadIdx.x, ty = threadIdx.y;
    #pragma unroll
    for (int i = ty; i < 32; i += 8)
        tile[i][tx] = Vf[(size_t)(b * 2048 + l0 + i) * 1024 + h * 64 + d0 + tx];
    __syncthreads();
    #pragma unroll
    for (int i = ty; i < 32; i += 8)
        Vt[((size_t)bh * 64 + d0 + i) * 2048 + l0 + tx] = tile[tx][i];
}

// ---------------------------------------------------------------------------
// C[M x N] = A[M x K] @ BT[N x K]^T   (bf16 in, OutT out)
// 128x128 tile, BK=64, 4 waves, swizzled LDS, mfma_f32_16x16x32_bf16
// ---------------------------------------------------------------------------
template <typename OutT>
__global__ __launch_bounds__(256, 2)
void gemm_bt(const u16* __restrict__ A, const u16* __restrict__ BT,
             OutT* __restrict__ C, int M, int N, int K,
             int lda, int ldb, int ldc) {
    __shared__ u16 As[128 * 64];
    __shared__ u16 Bs[128 * 64];
    const int tid = threadIdx.x;
    const int lane = tid & 63;
    const int wid = tid >> 6;
    const int m0 = blockIdx.x * 128;
    const int n0 = blockIdx.y * 128;
    const int wr = (wid >> 1) * 64;
    const int wc = (wid & 1) * 64;

    f32x4 acc[4][4];
    #pragma unroll
    for (int i = 0; i < 4; ++i)
        #pragma unroll
        for (int j = 0; j < 4; ++j)
            acc[i][j] = f32x4{0.f, 0.f, 0.f, 0.f};

    const int srow = tid >> 3;    // 0..31
    const int schunk = tid & 7;   // 16B chunk within row

    for (int k0 = 0; k0 < K; k0 += 64) {
        __syncthreads();
        #pragma unroll
        for (int p = 0; p < 4; ++p) {
            int row = p * 32 + srow;
            int4 v = *reinterpret_cast<const int4*>(A + (size_t)(m0 + row) * lda + k0 + schunk * 8);
            *reinterpret_cast<int4*>(reinterpret_cast<char*>(As) + swz(row, schunk * 16)) = v;
        }
        #pragma unroll
        for (int p = 0; p < 4; ++p) {
            int row = p * 32 + srow;
            int4 v = *reinterpret_cast<const int4*>(BT + (size_t)(n0 + row) * ldb + k0 + schunk * 8);
            *reinterpret_cast<int4*>(reinterpret_cast<char*>(Bs) + swz(row, schunk * 16)) = v;
        }
        __syncthreads();
        #pragma unroll
        for (int kk = 0; kk < 64; kk += 32) {
            bf16x8 af[4], bfr[4];
            #pragma unroll
            for (int i = 0; i < 4; ++i) {
                int row = wr + i * 16 + (lane & 15);
                af[i] = *reinterpret_cast<const bf16x8*>(
                    reinterpret_cast<const char*>(As) + swz(row, (kk + (lane >> 4) * 8) * 2));
            }
            #pragma unroll
            for (int j = 0; j < 4; ++j) {
                int row = wc + j * 16 + (lane & 15);
                bfr[j] = *reinterpret_cast<const bf16x8*>(
                    reinterpret_cast<const char*>(Bs) + swz(row, (kk + (lane >> 4) * 8) * 2));
            }
            #pragma unroll
            for (int i = 0; i < 4; ++i)
                #pragma unroll
                for (int j = 0; j < 4; ++j)
                    acc[i][j] = __builtin_amdgcn_mfma_f32_16x16x32_bf16(af[i], bfr[j], acc[i][j], 0, 0, 0);
        }
    }

    #pragma unroll
    for (int i = 0; i < 4; ++i)
        #pragma unroll
        for (int j = 0; j < 4; ++j)
            #pragma unroll
            for (int r = 0; r < 4; ++r) {
                int row = m0 + wr + i * 16 + (lane >> 4) * 4 + r;
                int col = n0 + wc + j * 16 + (lane & 15);
                store_c(&C[(size_t)row * ldc + col], acc[i][j][r]);
            }
}

// ---------------------------------------------------------------------------
// Sigmoid attention: out[b,h,q,:] = (sigma(QK^T*scale) @ V) / max(rowsum,1)
// grid (L/64, B*H), 4 waves; each wave owns 16 q-rows.
// ---------------------------------------------------------------------------
__global__ __launch_bounds__(256, 2)
void attn_kernel(const u16* __restrict__ Qf, const u16* __restrict__ Kf,
                 const u16* __restrict__ Vt, u16* __restrict__ Oa,
                 const float* __restrict__ temp) {
    constexpr int L = 2048, D = 1024, HD = 64;
    __shared__ u16 Qs[64 * 64];
    __shared__ u16 Ks[64 * 64];
    __shared__ u16 Vs[64 * 64];
    __shared__ u16 Ps[4][16 * 64];

    const int tid = threadIdx.x;
    const int lane = tid & 63;
    const int wid = tid >> 6;
    const int bh = blockIdx.y;
    const int b = bh >> 4, h = bh & 15;
    const int q0 = blockIdx.x * 64;
    const float scale = temp[0] * 0.125f;

    const u16* Qbase = Qf + (size_t)(b * L) * D + h * HD;
    const u16* Kbase = Kf + (size_t)(b * L) * D + h * HD;
    const u16* Vbase = Vt + (size_t)bh * HD * L;

    const int srow = tid >> 3;
    const int schunk = tid & 7;

    // stage Q once (visible after first loop-top barrier)
    #pragma unroll
    for (int p = 0; p < 2; ++p) {
        int row = p * 32 + srow;
        int4 v = *reinterpret_cast<const int4*>(Qbase + (size_t)(q0 + row) * D + schunk * 8);
        *reinterpret_cast<int4*>(reinterpret_cast<char*>(Qs) + swz(row, schunk * 16)) = v;
    }

    f32x4 oacc[4];
    #pragma unroll
    for (int j = 0; j < 4; ++j) oacc[j] = f32x4{0.f, 0.f, 0.f, 0.f};
    float rsum[4] = {0.f, 0.f, 0.f, 0.f};

    for (int k0 = 0; k0 < L; k0 += 64) {
        __syncthreads();   // prev iter done with Ks/Vs; Q visible on first iter
        #pragma unroll
        for (int p = 0; p < 2; ++p) {
            int row = p * 32 + srow;
            int4 v = *reinterpret_cast<const int4*>(Kbase + (size_t)(k0 + row) * D + schunk * 8);
            *reinterpret_cast<int4*>(reinterpret_cast<char*>(Ks) + swz(row, schunk * 16)) = v;
        }
        #pragma unroll
        for (int p = 0; p < 2; ++p) {
            int row = p * 32 + srow;   // output-channel c
            int4 v = *reinterpret_cast<const int4*>(Vbase + (size_t)row * L + k0 + schunk * 8);
            *reinterpret_cast<int4*>(reinterpret_cast<char*>(Vs) + swz(row, schunk * 16)) = v;
        }
        __syncthreads();

        // S = Q K^T for this wave's 16 q-rows x 64 keys
        f32x4 s[4];
        #pragma unroll
        for (int ct = 0; ct < 4; ++ct) s[ct] = f32x4{0.f, 0.f, 0.f, 0.f};
        #pragma unroll
        for (int kk = 0; kk < 64; kk += 32) {
            int qrow = wid * 16 + (lane & 15);
            bf16x8 aq = *reinterpret_cast<const bf16x8*>(
                reinterpret_cast<const char*>(Qs) + swz(qrow, (kk + (lane >> 4) * 8) * 2));
            #pragma unroll
            for (int ct = 0; ct < 4; ++ct) {
                int krow = ct * 16 + (lane & 15);
                bf16x8 bk = *reinterpret_cast<const bf16x8*>(
                    reinterpret_cast<const char*>(Ks) + swz(krow, (kk + (lane >> 4) * 8) * 2));
                s[ct] = __builtin_amdgcn_mfma_f32_16x16x32_bf16(aq, bk, s[ct], 0, 0, 0);
            }
        }

        // sigmoid, row-sum partials, P -> per-wave LDS (swizzled, C-layout transpose)
        #pragma unroll
        for (int ct = 0; ct < 4; ++ct) {
            #pragma unroll
            for (int r = 0; r < 4; ++r) {
                float pv = 1.0f / (1.0f + __expf(-s[ct][r] * scale));
                rsum[r] += pv;
                int prow = (lane >> 4) * 4 + r;
                *reinterpret_cast<u16*>(reinterpret_cast<char*>(Ps[wid]) +
                    swz(prow, (ct * 16 + (lane & 15)) * 2)) = f2bf(pv);
            }
        }
        // no barrier: Ps is per-wave (same-wave DS ops are in-order; compiler
        // cannot prove non-aliasing so it preserves program order)

        // O += P @ V
        #pragma unroll
        for (int kk = 0; kk < 64; kk += 32) {
            int prow = (lane & 15);
            bf16x8 ap = *reinterpret_cast<const bf16x8*>(
                reinterpret_cast<const char*>(Ps[wid]) + swz(prow, (kk + (lane >> 4) * 8) * 2));
            #pragma unroll
            for (int ct = 0; ct < 4; ++ct) {
                int vrow = ct * 16 + (lane & 15);   // output channel c
                bf16x8 bv = *reinterpret_cast<const bf16x8*>(
                    reinterpret_cast<const char*>(Vs) + swz(vrow, (kk + (lane >> 4) * 8) * 2));
                oacc[ct] = __builtin_amdgcn_mfma_f32_16x16x32_bf16(ap, bv, oacc[ct], 0, 0, 0);
            }
        }
    }

    // reduce row-sums across the 16 lanes sharing each C-row group
    #pragma unroll
    for (int r = 0; r < 4; ++r) {
        float v = rsum[r];
        v += __shfl_xor(v, 1);
        v += __shfl_xor(v, 2);
        v += __shfl_xor(v, 4);
        v += __shfl_xor(v, 8);
        rsum[r] = fmaxf(v, 1.0f);
    }

    #pragma unroll
    for (int ct = 0; ct < 4; ++ct)
        #pragma unroll
        for (int r = 0; r < 4; ++r) {
            int row = q0 + wid * 16 + (lane >> 4) * 4 + r;
            int col = h * HD + ct * 16 + (lane & 15);
            Oa[(size_t)(b * L + row) * D + col] = f2bf(oacc[ct][r] / rsum[r]);
        }
}

// ---------------------------------------------------------------------------
extern "C" void kernel_launch(void* const* d_in, const int* in_sizes, int n_in,
                              void* d_out, int out_size, void* d_ws, size_t ws_size,
                              hipStream_t stream) {
    const float* z    = (const float*)d_in[0];
    const float* cn   = (const float*)d_in[1];
    const float* Wq   = (const float*)d_in[2];
    const float* Wk   = (const float*)d_in[3];
    const float* Wv   = (const float*)d_in[4];
    const float* Wo   = (const float*)d_in[5];
    const float* temp = (const float*)d_in[6];

    // Workspace layout (92 MB total):
    //   zc is dead after the 3 projection GEMMs -> Vt aliases zc.
    //   Vf is dead after transpose_v            -> Oa aliases Vf.
    char* ws = (char*)d_ws;
    u16* zc  = (u16*)ws; ws += (size_t)8192 * 2048 * 2;   // 32 MB
    u16* WqT = (u16*)ws; ws += (size_t)1024 * 2048 * 2;   //  4 MB
    u16* WkT = (u16*)ws; ws += (size_t)1024 * 2048 * 2;   //  4 MB
    u16* WvT = (u16*)ws; ws += (size_t)1024 * 1024 * 2;   //  2 MB
    u16* WoT = (u16*)ws; ws += (size_t)1024 * 1024 * 2;   //  2 MB
    u16* Qf  = (u16*)ws; ws += (size_t)8192 * 1024 * 2;   // 16 MB
    u16* Kf  = (u16*)ws; ws += (size_t)8192 * 1024 * 2;   // 16 MB
    u16* Vf  = (u16*)ws; ws += (size_t)8192 * 1024 * 2;   // 16 MB
    u16* Vt  = zc;   // alias: zc dead after projections
    u16* Oa  = Vf;   // alias: Vf dead after transpose_v

    pack_zc<<<16384, 256, 0, stream>>>(z, cn, zc);

    dim3 tb(32, 8);
    transpose_conv_w<<<dim3(32, 64), tb, 0, stream>>>(Wq, WqT, 2048, 1024);
    transpose_conv_w<<<dim3(32, 64), tb, 0, stream>>>(Wk, WkT, 2048, 1024);
    transpose_conv_w<<<dim3(32, 32), tb, 0, stream>>>(Wv, WvT, 1024, 1024);
    transpose_conv_w<<<dim3(32, 32), tb, 0, stream>>>(Wo, WoT, 1024, 1024);

    gemm_bt<u16><<<dim3(64, 8), 256, 0, stream>>>(zc, WqT, Qf, 8192, 1024, 2048, 2048, 2048, 1024);
    gemm_bt<u16><<<dim3(64, 8), 256, 0, stream>>>(zc, WkT, Kf, 8192, 1024, 2048, 2048, 2048, 1024);
    gemm_bt<u16><<<dim3(64, 8), 256, 0, stream>>>(zc, WvT, Vf, 8192, 1024, 1024, 2048, 1024, 1024);

    transpose_v<<<dim3(64, 2, 64), tb, 0, stream>>>(Vf, Vt);

    attn_kernel<<<dim3(32, 64), 256, 0, stream>>>(Qf, Kf, Vt, Oa, temp);

    gemm_bt<float><<<dim3(64, 8), 256, 0, stream>>>(Oa, WoT, (float*)d_out, 8192, 1024, 1024, 1024, 1024, 1024);
}

// Round 3
// 413.847 us; speedup vs baseline: 1.1508x; 1.1508x over previous
//
#include <hip/hip_runtime.h>

typedef unsigned short u16;
typedef unsigned int u32;
typedef __bf16 bf16x8 __attribute__((ext_vector_type(8)));
typedef float f32x4 __attribute__((ext_vector_type(4)));

#define DEV static __device__ __forceinline__

// async global->LDS, 16B per lane; dest is wave-uniform base + lane*16
DEV void gload16(const void* g, void* l) {
    __builtin_amdgcn_global_load_lds(
        (const __attribute__((address_space(1))) void*)g,
        (__attribute__((address_space(3))) void*)l, 16, 0, 0);
}

DEV void store_c(float* p, float v) { *p = v; }
DEV void store_c(u16* p, float v) { *(__bf16*)p = (__bf16)v; }

// swizzled LDS byte offset: row stride 128B, XOR chunk bits with (row&7)
DEV int swz(int row, int bytecol) { return row * 128 + (bytecol ^ ((row & 7) << 4)); }

// ---------------------------------------------------------------------------
// pack zc = concat(z, connection) as bf16  [8192 x 2048]
// ---------------------------------------------------------------------------
__global__ void pack_zc(const float* __restrict__ z, const float* __restrict__ cn,
                        u16* __restrict__ zc) {
    size_t i = ((size_t)blockIdx.x * blockDim.x + threadIdx.x) * 4;
    size_t t = i >> 11;            // token
    int c = (int)(i & 2047);
    const float* src = (c < 1024) ? (z + t * 1024 + c) : (cn + t * 1024 + (c - 1024));
    float4 v = *reinterpret_cast<const float4*>(src);
    union { __bf16 h[4]; uint2 u; } o;
    o.h[0] = (__bf16)v.x; o.h[1] = (__bf16)v.y;
    o.h[2] = (__bf16)v.z; o.h[3] = (__bf16)v.w;
    *reinterpret_cast<uint2*>(zc + i) = o.u;
}

// ---------------------------------------------------------------------------
// W [K x N] fp32  ->  WT [N x K] bf16
// ---------------------------------------------------------------------------
__global__ void transpose_conv_w(const float* __restrict__ W, u16* __restrict__ WT,
                                 int K, int N) {
    __shared__ float tile[32][33];
    int n0 = blockIdx.x * 32, k0 = blockIdx.y * 32;
    int tx = threadIdx.x, ty = threadIdx.y;
    #pragma unroll
    for (int i = ty; i < 32; i += 8)
        tile[i][tx] = W[(size_t)(k0 + i) * N + n0 + tx];
    __syncthreads();
    #pragma unroll
    for (int i = ty; i < 32; i += 8)
        *(__bf16*)&WT[(size_t)(n0 + i) * K + k0 + tx] = (__bf16)tile[tx][i];
}

// ---------------------------------------------------------------------------
// Vflat [8192 x 1024] bf16 -> Vt [64(bh)][64(hd)][2048(L)] bf16
// ---------------------------------------------------------------------------
__global__ void transpose_v(const u16* __restrict__ Vf, u16* __restrict__ Vt) {
    __shared__ u16 tile[32][33];
    int bh = blockIdx.z; int b = bh >> 4, h = bh & 15;
    int l0 = blockIdx.x * 32, d0 = blockIdx.y * 32;
    int tx = threadIdx.x, ty = threadIdx.y;
    #pragma unroll
    for (int i = ty; i < 32; i += 8)
        tile[i][tx] = Vf[(size_t)(b * 2048 + l0 + i) * 1024 + h * 64 + d0 + tx];
    __syncthreads();
    #pragma unroll
    for (int i = ty; i < 32; i += 8)
        Vt[((size_t)bh * 64 + d0 + i) * 2048 + l0 + tx] = tile[tx][i];
}

// ---------------------------------------------------------------------------
// C[M x N] = A[M x K] @ BT[N x K]^T   (bf16 in, OutT out)
// 128x128 tile, BK=64, 4 waves, global_load_lds staging with pre-swizzled
// source (LDS[row][c] = global[row][c ^ (row&7)]), mfma_f32_16x16x32_bf16.
// ---------------------------------------------------------------------------
template <typename OutT>
__global__ __launch_bounds__(256, 2)
void gemm_bt(const u16* __restrict__ A, const u16* __restrict__ BT,
             OutT* __restrict__ C, int M, int N, int K,
             int lda, int ldb, int ldc) {
    __shared__ u16 As[128 * 64];
    __shared__ u16 Bs[128 * 64];
    const int tid = threadIdx.x;
    const int lane = tid & 63;
    const int wid = tid >> 6;
    const int m0 = blockIdx.x * 128;
    const int n0 = blockIdx.y * 128;
    const int wr = (wid >> 1) * 64;
    const int wc = (wid & 1) * 64;

    f32x4 acc[4][4];
    #pragma unroll
    for (int i = 0; i < 4; ++i)
        #pragma unroll
        for (int j = 0; j < 4; ++j)
            acc[i][j] = f32x4{0.f, 0.f, 0.f, 0.f};

    // staging geometry: slot = (wid*4+p)*64 + lane; row = slot>>3 = wid*32+p*8+(lane>>3)
    // row&7 == lane>>3, so source chunk = (lane&7) ^ (lane>>3) — lane constant.
    const int srcoff = ((lane & 7) ^ (lane >> 3)) * 8;   // elements
    const int rb = wid * 32 + (lane >> 3);
    const u16* aptr[4]; const u16* bptr[4];
    #pragma unroll
    for (int p = 0; p < 4; ++p) {
        aptr[p] = A  + (size_t)(m0 + rb + p * 8) * lda + srcoff;
        bptr[p] = BT + (size_t)(n0 + rb + p * 8) * ldb + srcoff;
    }

    for (int k0 = 0; k0 < K; k0 += 64) {
        __syncthreads();   // previous compute done before overwrite
        #pragma unroll
        for (int p = 0; p < 4; ++p)
            gload16(aptr[p] + k0, (char*)As + (wid * 4 + p) * 1024);
        #pragma unroll
        for (int p = 0; p < 4; ++p)
            gload16(bptr[p] + k0, (char*)Bs + (wid * 4 + p) * 1024);
        __syncthreads();   // staging complete (compiler drains vmcnt before barrier)

        #pragma unroll
        for (int kk = 0; kk < 64; kk += 32) {
            bf16x8 af[4], bfr[4];
            #pragma unroll
            for (int i = 0; i < 4; ++i) {
                int row = wr + i * 16 + (lane & 15);
                af[i] = *reinterpret_cast<const bf16x8*>(
                    reinterpret_cast<const char*>(As) + swz(row, (kk + (lane >> 4) * 8) * 2));
            }
            #pragma unroll
            for (int j = 0; j < 4; ++j) {
                int row = wc + j * 16 + (lane & 15);
                bfr[j] = *reinterpret_cast<const bf16x8*>(
                    reinterpret_cast<const char*>(Bs) + swz(row, (kk + (lane >> 4) * 8) * 2));
            }
            #pragma unroll
            for (int i = 0; i < 4; ++i)
                #pragma unroll
                for (int j = 0; j < 4; ++j)
                    acc[i][j] = __builtin_amdgcn_mfma_f32_16x16x32_bf16(af[i], bfr[j], acc[i][j], 0, 0, 0);
        }
    }

    #pragma unroll
    for (int i = 0; i < 4; ++i)
        #pragma unroll
        for (int j = 0; j < 4; ++j)
            #pragma unroll
            for (int r = 0; r < 4; ++r) {
                int row = m0 + wr + i * 16 + (lane >> 4) * 4 + r;
                int col = n0 + wc + j * 16 + (lane & 15);
                store_c(&C[(size_t)row * ldc + col], acc[i][j][r]);
            }
}

// ---------------------------------------------------------------------------
// Sigmoid attention: out[b,h,q,:] = (sigma(QK^T*scale) @ V) / max(rowsum,1)
// Q and K live interleaved in QKf [8192 x 2048] (cols 0-1023 Q, 1024-2047 K).
// grid (L/64, B*H), 4 waves; each wave owns 16 q-rows.
// rsum computed via MFMA with an all-ones B operand (C rows == oacc rows).
// ---------------------------------------------------------------------------
__global__ __launch_bounds__(256, 2)
void attn_kernel(const u16* __restrict__ QKf, const u16* __restrict__ Vt,
                 u16* __restrict__ Oa, const float* __restrict__ temp) {
    constexpr int L = 2048, D = 1024, QKLD = 2048, HD = 64;
    __shared__ u16 Qs[64 * 64];
    __shared__ u16 Ks[64 * 64];
    __shared__ u16 Vs[64 * 64];
    __shared__ u16 Ps[4][16 * 64];

    const int tid = threadIdx.x;
    const int lane = tid & 63;
    const int wid = tid >> 6;
    const int bh = blockIdx.y;
    const int b = bh >> 4, h = bh & 15;
    const int q0 = blockIdx.x * 64;
    const float sneg = -temp[0] * 0.125f * 1.44269504f;   // exp2-domain scale

    const u16* Qbase = QKf + (size_t)(b * L) * QKLD + h * HD;
    const u16* Kbase = Qbase + 1024;
    const u16* Vbase = Vt + (size_t)bh * HD * L;

    // staging geometry (64-row tiles): slot = (wid*2+p)*64+lane;
    // row = wid*16+p*8+(lane>>3); row&7 == lane>>3 -> src chunk = (lane&7)^(lane>>3)
    const int srcoff = ((lane & 7) ^ (lane >> 3)) * 8;
    const int rb = wid * 16 + (lane >> 3);

    // stage Q once (drained by the first barrier inside the loop)
    #pragma unroll
    for (int p = 0; p < 2; ++p)
        gload16(Qbase + (size_t)(q0 + rb + p * 8) * QKLD + srcoff,
                (char*)Qs + (wid * 2 + p) * 1024);

    const u16* kptr[2]; const u16* vptr[2];
    #pragma unroll
    for (int p = 0; p < 2; ++p) {
        kptr[p] = Kbase + (size_t)(rb + p * 8) * QKLD + srcoff;
        vptr[p] = Vbase + (size_t)(rb + p * 8) * L + srcoff;
    }

    bf16x8 onesf;
    #pragma unroll
    for (int j = 0; j < 8; ++j) onesf[j] = (__bf16)1.0f;

    f32x4 oacc[4];
    #pragma unroll
    for (int j = 0; j < 4; ++j) oacc[j] = f32x4{0.f, 0.f, 0.f, 0.f};
    f32x4 racc = f32x4{0.f, 0.f, 0.f, 0.f};

    for (int k0 = 0; k0 < L; k0 += 64) {
        __syncthreads();   // prev iter done with Ks/Vs
        #pragma unroll
        for (int p = 0; p < 2; ++p)
            gload16(kptr[p] + (size_t)k0 * QKLD, (char*)Ks + (wid * 2 + p) * 1024);
        #pragma unroll
        for (int p = 0; p < 2; ++p)
            gload16(vptr[p] + k0, (char*)Vs + (wid * 2 + p) * 1024);
        __syncthreads();   // staging complete

        // S = Q K^T for this wave's 16 q-rows x 64 keys
        f32x4 s[4];
        #pragma unroll
        for (int ct = 0; ct < 4; ++ct) s[ct] = f32x4{0.f, 0.f, 0.f, 0.f};
        #pragma unroll
        for (int kk = 0; kk < 64; kk += 32) {
            int qrow = wid * 16 + (lane & 15);
            bf16x8 aq = *reinterpret_cast<const bf16x8*>(
                reinterpret_cast<const char*>(Qs) + swz(qrow, (kk + (lane >> 4) * 8) * 2));
            #pragma unroll
            for (int ct = 0; ct < 4; ++ct) {
                int krow = ct * 16 + (lane & 15);
                bf16x8 bk = *reinterpret_cast<const bf16x8*>(
                    reinterpret_cast<const char*>(Ks) + swz(krow, (kk + (lane >> 4) * 8) * 2));
                s[ct] = __builtin_amdgcn_mfma_f32_16x16x32_bf16(aq, bk, s[ct], 0, 0, 0);
            }
        }

        // sigmoid -> bf16 P in per-wave LDS (swizzled transpose through LDS)
        #pragma unroll
        for (int ct = 0; ct < 4; ++ct) {
            #pragma unroll
            for (int r = 0; r < 4; ++r) {
                float pv = __builtin_amdgcn_rcpf(1.0f + exp2f(s[ct][r] * sneg));
                int prow = (lane >> 4) * 4 + r;
                *(__bf16*)(reinterpret_cast<char*>(Ps[wid]) +
                    swz(prow, (ct * 16 + (lane & 15)) * 2)) = (__bf16)pv;
            }
        }
        // no barrier: Ps is per-wave (same-wave DS ops are in-order)

        // O += P @ V ; rsum += P @ ones (same A fragment, matrix pipe)
        #pragma unroll
        for (int kk = 0; kk < 64; kk += 32) {
            int prow = (lane & 15);
            bf16x8 ap = *reinterpret_cast<const bf16x8*>(
                reinterpret_cast<const char*>(Ps[wid]) + swz(prow, (kk + (lane >> 4) * 8) * 2));
            racc = __builtin_amdgcn_mfma_f32_16x16x32_bf16(ap, onesf, racc, 0, 0, 0);
            #pragma unroll
            for (int ct = 0; ct < 4; ++ct) {
                int vrow = ct * 16 + (lane & 15);   // output channel c
                bf16x8 bv = *reinterpret_cast<const bf16x8*>(
                    reinterpret_cast<const char*>(Vs) + swz(vrow, (kk + (lane >> 4) * 8) * 2));
                oacc[ct] = __builtin_amdgcn_mfma_f32_16x16x32_bf16(ap, bv, oacc[ct], 0, 0, 0);
            }
        }
    }

    float rdiv[4];
    #pragma unroll
    for (int r = 0; r < 4; ++r)
        rdiv[r] = __builtin_amdgcn_rcpf(fmaxf(racc[r], 1.0f));

    #pragma unroll
    for (int ct = 0; ct < 4; ++ct)
        #pragma unroll
        for (int r = 0; r < 4; ++r) {
            int row = q0 + wid * 16 + (lane >> 4) * 4 + r;
            int col = h * HD + ct * 16 + (lane & 15);
            *(__bf16*)&Oa[(size_t)(b * L + row) * D + col] = (__bf16)(oacc[ct][r] * rdiv[r]);
        }
}

// ---------------------------------------------------------------------------
extern "C" void kernel_launch(void* const* d_in, const int* in_sizes, int n_in,
                              void* d_out, int out_size, void* d_ws, size_t ws_size,
                              hipStream_t stream) {
    const float* z    = (const float*)d_in[0];
    const float* cn   = (const float*)d_in[1];
    const float* Wq   = (const float*)d_in[2];
    const float* Wk   = (const float*)d_in[3];
    const float* Wv   = (const float*)d_in[4];
    const float* Wo   = (const float*)d_in[5];
    const float* Wo_  = (const float*)d_in[5];
    const float* temp = (const float*)d_in[6];
    (void)Wo_;

    // Workspace layout (92 MB total):
    //   WqT and WkT MUST stay contiguous (merged QK GEMM reads them as one
    //   [2048][2048] BT matrix).
    //   zc dead after projections -> Vt aliases zc.
    //   Vf dead after transpose_v -> Oa aliases Vf.
    char* ws = (char*)d_ws;
    u16* zc  = (u16*)ws; ws += (size_t)8192 * 2048 * 2;   // 32 MB
    u16* WqT = (u16*)ws; ws += (size_t)1024 * 2048 * 2;   //  4 MB
    u16* WkT = (u16*)ws; ws += (size_t)1024 * 2048 * 2;   //  4 MB (contiguous after WqT)
    u16* WvT = (u16*)ws; ws += (size_t)1024 * 1024 * 2;   //  2 MB
    u16* WoT = (u16*)ws; ws += (size_t)1024 * 1024 * 2;   //  2 MB
    u16* QKf = (u16*)ws; ws += (size_t)8192 * 2048 * 2;   // 32 MB (Q cols 0-1023, K cols 1024-2047)
    u16* Vf  = (u16*)ws; ws += (size_t)8192 * 1024 * 2;   // 16 MB
    u16* Vt  = zc;   // alias: zc dead after projections
    u16* Oa  = Vf;   // alias: Vf dead after transpose_v

    pack_zc<<<16384, 256, 0, stream>>>(z, cn, zc);

    dim3 tb(32, 8);
    transpose_conv_w<<<dim3(32, 64), tb, 0, stream>>>(Wq, WqT, 2048, 1024);
    transpose_conv_w<<<dim3(32, 64), tb, 0, stream>>>(Wk, WkT, 2048, 1024);
    transpose_conv_w<<<dim3(32, 32), tb, 0, stream>>>(Wv, WvT, 1024, 1024);
    transpose_conv_w<<<dim3(32, 32), tb, 0, stream>>>(Wo, WoT, 1024, 1024);

    // merged Q+K projection: [8192,2048] @ [2048,2048]^T -> QKf
    gemm_bt<u16><<<dim3(64, 16), 256, 0, stream>>>(zc, WqT, QKf, 8192, 2048, 2048, 2048, 2048, 2048);
    gemm_bt<u16><<<dim3(64, 8),  256, 0, stream>>>(zc, WvT, Vf,  8192, 1024, 1024, 2048, 1024, 1024);

    transpose_v<<<dim3(64, 2, 64), tb, 0, stream>>>(Vf, Vt);

    attn_kernel<<<dim3(32, 64), 256, 0, stream>>>(QKf, Vt, Oa, temp);

    gemm_bt<float><<<dim3(64, 8), 256, 0, stream>>>(Oa, WoT, (float*)d_out, 8192, 1024, 1024, 1024, 1024, 1024);
}